// Round 7
// baseline (159.617 us; speedup 1.0000x reference)
//
#include <hip/hip_runtime.h>
#include <math.h>

static constexpr int BB  = 4;
static constexpr int HH  = 1024;
static constexpr int WW  = 1024;
static constexpr int HWP = HH * WW;       // 1<<20
static constexpr int NPIX = BB * HWP;     // 4<<20
static constexpr int WPR = WW / 64;       // 16 words per image row
static constexpr int PW  = HWP / 64;      // 16384 words per image bitplane
static constexpr int ROUNDS = 6;          // 6 rounds @256px tiles >= 6 rounds @128px (passed r6)
static constexpr int NT  = BB * 4 * 4;    // 64 hysteresis tiles (256x256 px, one BLOCK each)
static constexpr int RF  = ROUNDS + 1;    // flags array length
static constexpr int FCN = RF + RF * NT;  // flags[RF] + dirt[RF][NT]

// fused-stencil tile: 64 wide x 8 tall output; f64 LDS ~18.4 KB -> 8 blocks/CU
static constexpr int TX = 64, TY = 8;
static constexpr int GH = 16,  GW = 72;   // gray   (pre-reflected halo)  TY+8
static constexpr int HBH = 16, HBW = 68;  // hblur                        TY+8
static constexpr int VBH = 12, VBW = 68;  // vblur                        TY+4
static constexpr int MGH = 10, MGW = 66;  // mag^2                        TY+2

__device__ __forceinline__ int reflect_idx(int i, int n) {
    i = (i < 0) ? -i : i;                 // jnp.pad mode='reflect': -1 -> 1
    return (i >= n) ? (2 * n - 2 - i) : i;
}

// ---------- fused: gray -> hblur -> vblur -> sobel/mag^2 -> dir -> NMS -> ballot ----------
// f64 throughout (validated): f32 blur flips near-tie NMS decisions vs the reference.
__global__ void __launch_bounds__(256) k_front(const float* __restrict__ x,
                                               float* __restrict__ out0,
                                               unsigned long long* __restrict__ weakP,
                                               unsigned long long* __restrict__ strongP,
                                               int* __restrict__ fc,
                                               double w0, double w1, double w2) {
    __shared__ double A[GH * GW];         // gray, then vblur
    __shared__ double B[HBH * HBW];       // hblur, then mag^2
    __shared__ unsigned char P[TY * TX];  // quantized direction, center pixels

    const int tid = threadIdx.x;
    const int x0  = blockIdx.x * TX;
    const int y0  = blockIdx.y * TY;
    const int b   = blockIdx.z;
    const float* base = x + (size_t)b * 3u * HWP;

    if (blockIdx.x == 0 && blockIdx.y == 0 && b == 0) {
        // flags[0]=1, dirt[0][*]=1, rest 0
        for (int i = tid; i < FCN; i += 256)
            fc[i] = (i == 0 || (i >= RF && i < RF + NT)) ? 1 : 0;
    }

    // S1: grayscale into A (rows/cols pre-reflected so later reads are raw)
    for (int idx = tid; idx < GH * GW; idx += 256) {
        int r = idx / GW, c = idx - r * GW;
        int gyr = reflect_idx(y0 + r - 4, HH);
        int gxr = reflect_idx(x0 + c - 4, WW);
        const float* rp = base + (size_t)gyr * WW;
        double rr = (double)rp[gxr];
        double gg = (double)rp[HWP + gxr];
        double bb = (double)rp[2 * HWP + gxr];
        A[idx] = rr * 0.299 + gg * 0.587 + bb * 0.114;
    }
    __syncthreads();

    // S2: hblur into B
    for (int idx = tid; idx < HBH * HBW; idx += 256) {
        int r = idx / HBW, c = idx - r * HBW;
        const double* g = &A[r * GW + c];
        double s;
        s  = w0 * g[0];
        s += w1 * g[1];
        s += w2 * g[2];
        s += w1 * g[3];
        s += w0 * g[4];
        B[idx] = s;
    }
    __syncthreads();

    // S3: vblur into A
    for (int idx = tid; idx < VBH * VBW; idx += 256) {
        int r = idx / VBW, c = idx - r * VBW;
        const double* h = &B[r * HBW + c];
        double s;
        s  = w0 * h[0];
        s += w1 * h[1 * HBW];
        s += w2 * h[2 * HBW];
        s += w1 * h[3 * HBW];
        s += w0 * h[4 * HBW];
        A[idx] = s;
    }
    __syncthreads();

    // S4: SQUARED sobel magnitude into B (0 outside image = NMS zero pad) + dir bytes.
    for (int idx = tid; idx < MGH * MGW; idx += 256) {
        int r = idx / MGW, c = idx - r * MGW;
        int gy = y0 + r - 1, gx = x0 + c - 1;
        double mg2 = 0.0;
        if (gy >= 0 && gy < HH && gx >= 0 && gx < WW) {
            int ym = gy > 0 ? gy - 1 : 0, yp = gy < HH - 1 ? gy + 1 : HH - 1;
            int xm = gx > 0 ? gx - 1 : 0, xp = gx < WW - 1 ? gx + 1 : WW - 1;
            auto BL = [&](int yy, int xx) -> double {
                return A[(yy - y0 + 2) * VBW + (xx - x0 + 2)];
            };
            double b00 = BL(ym, xm), b01 = BL(ym, gx), b02 = BL(ym, xp);
            double b10 = BL(gy, xm),                   b12 = BL(gy, xp);
            double b20 = BL(yp, xm), b21 = BL(yp, gx), b22 = BL(yp, xp);
            double gxv = -b00 + b02 - 2.0 * b10 + 2.0 * b12 - b20 + b22;
            double gyv = -b00 - 2.0 * b01 - b02 + b20 + 2.0 * b21 + b22;
            mg2 = gxv * gxv + gyv * gyv + 1e-6;
            if (r >= 1 && r < TY + 1 && c >= 1 && c < TX + 1) {
                // octant classification == round(atan2(gy,gx)*4/pi) mod 8, boundary-exact
                double ax = fabs(gxv), ay = fabs(gyv);
                int p;
                if (ay < 0.41421356237309503 * ax)       // tan(22.5deg)
                    p = (gxv >= 0.0) ? 0 : 4;
                else if (ay < 2.4142135623730951 * ax)   // tan(67.5deg)
                    p = (gyv >= 0.0) ? ((gxv >= 0.0) ? 1 : 3)
                                     : ((gxv >= 0.0) ? 7 : 5);
                else
                    p = (gyv >= 0.0) ? 2 : 6;
                P[(r - 1) * TX + (c - 1)] = (unsigned char)p;
            }
        }
        B[r * MGW + c] = mg2;
    }
    __syncthreads();

    // S5: NMS + thresholds + ballot on squared magnitudes (one wave = one 64px row-word)
    for (int k = 0; k < (TX * TY) / 256; ++k) {
        int idx = k * 256 + tid;
        int r = idx >> 6, c = idx & 63;
        double ctr2 = B[(r + 1) * MGW + (c + 1)];
        int p = P[idx];
        int dr = ((425   >> (2 * p)) & 3) - 1;
        int dc = ((36890 >> (2 * p)) & 3) - 1;
        double mp2 = B[(r + 1 + dr) * MGW + (c + 1 + dc)];
        double mn2 = B[(r + 1 - dr) * MGW + (c + 1 - dc)];
        bool ismax = (ctr2 > mp2) && (ctr2 > mn2);      // sqrt is monotone -> same booleans
        out0[(size_t)b * HWP + (size_t)(y0 + r) * WW + (x0 + c)] =
            ismax ? (float)sqrt(ctr2) : 0.0f;
        bool strong = ismax && (ctr2 > 0.04);           // sm > 0.2
        bool weak   = ismax && (ctr2 > 0.01) && !strong;// sm > 0.1
        unsigned long long wb = __ballot(weak);
        unsigned long long sb = __ballot(strong);
        if ((tid & 63) == 0) {
            int word = (y0 + r) * WPR + (x0 >> 6);
            weakP[(size_t)b * PW + word]   = wb;
            strongP[(size_t)b * PW + word] = sb;
        }
    }
}

// ---------------- hysteresis: block-per-256x256-tile flood fill, 4 words/lane ----------------
__device__ __forceinline__ unsigned long long ks_fill(unsigned long long g, unsigned long long p) {
    unsigned long long q;
    q = p;        g |= q & (g << 1);
    q &= q << 1;  g |= q & (g << 2);
    q &= q << 2;  g |= q & (g << 4);
    q &= q << 4;  g |= q & (g << 8);
    q &= q << 8;  g |= q & (g << 16);
    q &= q << 16; g |= q & (g << 32);
    q = p;        g |= q & (g >> 1);
    q &= q >> 1;  g |= q & (g >> 2);
    q &= q >> 2;  g |= q & (g >> 4);
    q &= q >> 4;  g |= q & (g >> 8);
    q &= q >> 8;  g |= q & (g >> 16);
    q &= q >> 16; g |= q & (g >> 32);
    return g;
}

// 64 blocks x 256 threads; block = one 256x256 tile (4 waves x 64 rows; 4 words/lane).
// The 4 word-columns are independent dependency chains -> ILP=4 in the latency-bound
// inner loop (1 wave/SIMD regime). Inter-wave coupling via boundary rows in LDS only.
// Coverage: every 256-boundary is a 128-boundary, so round k here dominates round k of
// the 128-tile scheme that passed at ROUNDS=6 -> same fixed point within 6 rounds.
// Final round writes out1 (fused k_edges).
__global__ void __launch_bounds__(256) k_pass(const unsigned long long* __restrict__ weakP,
                                              unsigned long long* __restrict__ strongP,
                                              int* __restrict__ flags,
                                              int* __restrict__ dirt,
                                              float* __restrict__ out1, int rr) {
    __shared__ unsigned long long S[256][4];          // full tile (final write only)
    __shared__ unsigned long long Btop[4][4], Bbot[4][4]; // per-wave boundary spread rows
    __shared__ int chf[4];

    const int tid  = threadIdx.x;
    const int lane = tid & 63;
    const int w    = tid >> 6;            // wave in block 0..3 (row strip)
    const int tile = blockIdx.x;          // 0..63
    const int b  = tile >> 4;
    const int ty = (tile >> 2) & 3;
    const int tx = tile & 3;
    const int tb = b << 4;

    const bool active = (flags[rr - 1] != 0);
    if (!active && rr != ROUNDS) return;  // globally quiet; nothing to do until final write

    int go = 0;
    if (active) {                         // 3x3 ring on the 4x4 tile grid
        const int* d0 = dirt + (size_t)(rr - 1) * NT;
        for (int dy = -1; dy <= 1; ++dy) {
            int yy = ty + dy;
            if (yy < 0 || yy > 3) continue;
            for (int dx = -1; dx <= 1; ++dx) {
                int xx = tx + dx;
                if (xx < 0 || xx > 3 || (dy == 0 && dx == 0)) continue;
                go |= d0[tb + (yy << 2) + xx];
            }
        }
    }

    unsigned long long* spl      = strongP + (size_t)b * PW;
    const unsigned long long* wp = weakP + (size_t)b * PW;
    const int lr   = (w << 6) + lane;     // tile row 0..255
    const int row  = (ty << 8) + lr;      // image row
    const int wc0  = tx << 2;             // first image word of tile (0..15)
    const int base = row * WPR + wc0;

    unsigned long long s0, s1, s2, s3;

    if (go) {                                        // block-uniform
        unsigned long long wv0 = wp[base + 0], wv1 = wp[base + 1];
        unsigned long long wv2 = wp[base + 2], wv3 = wp[base + 3];
        s0 = spl[base + 0]; s1 = spl[base + 1];
        s2 = spl[base + 2]; s3 = spl[base + 3];

        // static external left/right bits, per row (Jacobi; fresh reads benign)
        unsigned long long hoL = 0, hoR = 0;
        if (tx > 0) hoL = spl[base - 1] >> 63;
        if (tx < 3) hoR = spl[base + 4] << 63;

        // static external top/bottom spread rows (used by lane0/w0 and lane63/w3)
        unsigned long long topE[4] = {0, 0, 0, 0}, botE[4] = {0, 0, 0, 0};
        if (w == 0 && lane == 0 && ty > 0) {
            int ra = (row - 1) * WPR;
            unsigned long long h[6];
            for (int k = 0; k < 6; ++k) {
                int wq = wc0 + k - 1;
                h[k] = (wq >= 0 && wq < WPR) ? spl[ra + wq] : 0ull;
            }
            for (int j = 0; j < 4; ++j)
                topE[j] = (h[j+1] << 1) | h[j+1] | (h[j+1] >> 1) | (h[j] >> 63) | (h[j+2] << 63);
        }
        if (w == 3 && lane == 63 && ty < 3) {
            int ra = (row + 1) * WPR;
            unsigned long long h[6];
            for (int k = 0; k < 6; ++k) {
                int wq = wc0 + k - 1;
                h[k] = (wq >= 0 && wq < WPR) ? spl[ra + wq] : 0ull;
            }
            for (int j = 0; j < 4; ++j)
                botE[j] = (h[j+1] << 1) | h[j+1] | (h[j+1] >> 1) | (h[j] >> 63) | (h[j+2] << 63);
        }

        // prologue: publish boundary spread rows
        if (lane == 0 || lane == 63) {
            unsigned long long o0 = (s0 << 1) | s0 | (s0 >> 1) | hoL | (s1 << 63);
            unsigned long long o1 = (s1 << 1) | s1 | (s1 >> 1) | (s0 >> 63) | (s2 << 63);
            unsigned long long o2 = (s2 << 1) | s2 | (s2 >> 1) | (s1 >> 63) | (s3 << 63);
            unsigned long long o3 = (s3 << 1) | s3 | (s3 >> 1) | (s2 >> 63) | hoR;
            if (lane == 0)  { Btop[w][0] = o0; Btop[w][1] = o1; Btop[w][2] = o2; Btop[w][3] = o3; }
            else            { Bbot[w][0] = o0; Bbot[w][1] = o1; Bbot[w][2] = o2; Bbot[w][3] = o3; }
        }
        __syncthreads();

        int blkchanged = 0;
        for (;;) {
            // read inter-wave halos (LDS) / external halos
            unsigned long long up0 = 0, up1 = 0, up2 = 0, up3 = 0;
            unsigned long long dn0 = 0, dn1 = 0, dn2 = 0, dn3 = 0;
            if (lane == 0) {
                if (w > 0) { up0 = Bbot[w-1][0]; up1 = Bbot[w-1][1]; up2 = Bbot[w-1][2]; up3 = Bbot[w-1][3]; }
                else       { up0 = topE[0]; up1 = topE[1]; up2 = topE[2]; up3 = topE[3]; }
            }
            if (lane == 63) {
                if (w < 3) { dn0 = Btop[w+1][0]; dn1 = Btop[w+1][1]; dn2 = Btop[w+1][2]; dn3 = Btop[w+1][3]; }
                else       { dn0 = botE[0]; dn1 = botE[1]; dn2 = botE[2]; dn3 = botE[3]; }
            }

            // wave-local fixed point: shuffles vertical, ks_fill horizontal (ILP-4 words)
            int innerch = 0;
            for (;;) {
                unsigned long long sp0 = (s0 << 1) | s0 | (s0 >> 1) | hoL | (s1 << 63);
                unsigned long long sp1 = (s1 << 1) | s1 | (s1 >> 1) | (s0 >> 63) | (s2 << 63);
                unsigned long long sp2 = (s2 << 1) | s2 | (s2 >> 1) | (s1 >> 63) | (s3 << 63);
                unsigned long long sp3 = (s3 << 1) | s3 | (s3 >> 1) | (s2 >> 63) | hoR;
                unsigned long long u0 = __shfl_up(sp0, 1), d0 = __shfl_down(sp0, 1);
                unsigned long long u1 = __shfl_up(sp1, 1), d1 = __shfl_down(sp1, 1);
                unsigned long long u2 = __shfl_up(sp2, 1), d2 = __shfl_down(sp2, 1);
                unsigned long long u3 = __shfl_up(sp3, 1), d3 = __shfl_down(sp3, 1);
                if (lane == 0)  { u0 = up0; u1 = up1; u2 = up2; u3 = up3; }
                if (lane == 63) { d0 = dn0; d1 = dn1; d2 = dn2; d3 = dn3; }
                unsigned long long g0 = ks_fill(s0 | (wv0 & (u0 | sp0 | d0)), wv0);
                unsigned long long g1 = ks_fill(s1 | (wv1 & (u1 | sp1 | d1)), wv1);
                unsigned long long g2 = ks_fill(s2 | (wv2 & (u2 | sp2 | d2)), wv2);
                unsigned long long g3 = ks_fill(s3 | (wv3 & (u3 | sp3 | d3)), wv3);
                int ch = (g0 != s0) | (g1 != s1) | (g2 != s2) | (g3 != s3);
                s0 = g0; s1 = g1; s2 = g2; s3 = g3;
                if (!__any(ch)) break;
                innerch = 1;                         // uniform
            }

            if (lane == 0) chf[w] = innerch;
            __syncthreads();                         // (A) halo reads done; chf written
            if (lane == 0 || lane == 63) {           // publish new boundary rows
                unsigned long long o0 = (s0 << 1) | s0 | (s0 >> 1) | hoL | (s1 << 63);
                unsigned long long o1 = (s1 << 1) | s1 | (s1 >> 1) | (s0 >> 63) | (s2 << 63);
                unsigned long long o2 = (s2 << 1) | s2 | (s2 >> 1) | (s1 >> 63) | (s3 << 63);
                unsigned long long o3 = (s3 << 1) | s3 | (s3 >> 1) | (s2 >> 63) | hoR;
                if (lane == 0)  { Btop[w][0] = o0; Btop[w][1] = o1; Btop[w][2] = o2; Btop[w][3] = o3; }
                else            { Bbot[w][0] = o0; Bbot[w][1] = o1; Bbot[w][2] = o2; Bbot[w][3] = o3; }
            }
            int any = chf[0] | chf[1] | chf[2] | chf[3];
            if (any) blkchanged = 1;
            __syncthreads();                         // (B) publishes visible; chf reads done
            if (!any) break;
        }

        if (blkchanged) {
            spl[base + 0] = s0; spl[base + 1] = s1;  // republish for next Jacobi round
            spl[base + 2] = s2; spl[base + 3] = s3;
            if (tid == 0) {
                dirt[(size_t)rr * NT + tb + (ty << 2) + tx] = 1;
                atomicOr(&flags[rr], 1);
            }
        }
    }

    // fused k_edges on the final round: write this block's 256x256 tile as floats.
    if (rr == ROUNDS) {
        if (go) { S[lr][0] = s0; S[lr][1] = s1; S[lr][2] = s2; S[lr][3] = s3; }
        else    { S[lr][0] = spl[base + 0]; S[lr][1] = spl[base + 1];
                  S[lr][2] = spl[base + 2]; S[lr][3] = spl[base + 3]; }
        __syncthreads();
        float* o = out1 + (size_t)b * HWP;
        for (int it = 0; it < 64; ++it) {
            int fi = (it << 8) + tid;        // float4 index within tile: 0..16383
            int r  = fi >> 6;                // 0..255
            int c4 = fi & 63;                // float4 column 0..63
            unsigned long long bits = S[r][c4 >> 4];
            int sh = (c4 & 15) << 2;
            float4 v;
            v.x = ((bits >> (sh + 0)) & 1ull) ? 1.0f : 0.0f;
            v.y = ((bits >> (sh + 1)) & 1ull) ? 1.0f : 0.0f;
            v.z = ((bits >> (sh + 2)) & 1ull) ? 1.0f : 0.0f;
            v.w = ((bits >> (sh + 3)) & 1ull) ? 1.0f : 0.0f;
            int grow = (ty << 8) + r;
            int gcol = (tx << 8) + (c4 << 2);
            *reinterpret_cast<float4*>(&o[(size_t)grow * WW + gcol]) = v;
        }
    }
}

extern "C" void kernel_launch(void* const* d_in, const int* in_sizes, int n_in,
                              void* d_out, int out_size, void* d_ws, size_t ws_size,
                              hipStream_t stream) {
    const float* x = (const float*)d_in[0];
    float* out0 = (float*)d_out;          // suppressed magnitude [4,1,1024,1024]
    float* out1 = out0 + NPIX;            // edges [4,1,1024,1024]

    // workspace: weakP | strongP | fc (flags[RF] + dirt[RF][NT])
    unsigned long long* weakP   = (unsigned long long*)d_ws;
    unsigned long long* strongP = weakP + (size_t)BB * PW;
    int* fc    = (int*)(strongP + (size_t)BB * PW);
    int* flags = fc;
    int* dirt  = fc + RF;

    // gaussian weights, f64 ops mirroring the reference
    double g0 = exp(-2.0), g1 = exp(-0.5), g2 = 1.0;
    double sum = (((g0 + g1) + g2) + g1) + g0;
    double w0 = g0 / sum, w1 = g1 / sum, w2 = g2 / sum;

    k_front<<<dim3(WW / TX, HH / TY, BB), dim3(256), 0, stream>>>(
        x, out0, weakP, strongP, fc, w0, w1, w2);

    for (int r = 1; r <= ROUNDS; ++r)
        k_pass<<<dim3(NT), dim3(256), 0, stream>>>(weakP, strongP, flags, dirt, out1, r);
}

// Round 8
// 155.121 us; speedup vs baseline: 1.0290x; 1.0290x over previous
//
#include <hip/hip_runtime.h>
#include <math.h>

static constexpr int BB  = 4;
static constexpr int HH  = 1024;
static constexpr int WW  = 1024;
static constexpr int HWP = HH * WW;       // 1<<20
static constexpr int NPIX = BB * HWP;     // 4<<20
static constexpr int WPR = WW / 64;       // 16 words per image row
static constexpr int PW  = HWP / 64;      // 16384 words per image bitplane
static constexpr int ROUNDS = 6;          // 6 rounds @128px tiles (validated round 6)
static constexpr int NT  = BB * 8 * 8;    // 256 hysteresis tiles (128x128 px, one BLOCK each)
static constexpr int RF  = ROUNDS + 1;    // flags array length
static constexpr int FCN = RF + RF * NT;  // flags[RF] + dirt[RF][NT]

// fused-stencil tile: 64 wide x 8 tall output; f64 LDS ~18.4 KB -> 8 blocks/CU
static constexpr int TX = 64, TY = 8;
static constexpr int GH = 16,  GW = 72;   // gray   (pre-reflected halo)  TY+8
static constexpr int HBH = 16, HBW = 68;  // hblur                        TY+8
static constexpr int VBH = 12, VBW = 68;  // vblur                        TY+4
static constexpr int MGH = 10, MGW = 66;  // mag^2                        TY+2

__device__ __forceinline__ int reflect_idx(int i, int n) {
    i = (i < 0) ? -i : i;                 // jnp.pad mode='reflect': -1 -> 1
    return (i >= n) ? (2 * n - 2 - i) : i;
}

// ---------- fused: gray -> hblur -> vblur -> sobel/mag^2 -> dir -> NMS -> ballot ----------
// f64 throughout (validated): f32 blur flips near-tie NMS decisions vs the reference.
__global__ void __launch_bounds__(256) k_front(const float* __restrict__ x,
                                               float* __restrict__ out0,
                                               unsigned long long* __restrict__ weakP,
                                               unsigned long long* __restrict__ strongP,
                                               int* __restrict__ fc,
                                               double w0, double w1, double w2) {
    __shared__ double A[GH * GW];         // gray, then vblur
    __shared__ double B[HBH * HBW];       // hblur, then mag^2
    __shared__ unsigned char P[TY * TX];  // quantized direction, center pixels

    const int tid = threadIdx.x;
    const int x0  = blockIdx.x * TX;
    const int y0  = blockIdx.y * TY;
    const int b   = blockIdx.z;
    const float* base = x + (size_t)b * 3u * HWP;

    if (blockIdx.x == 0 && blockIdx.y == 0 && b == 0) {
        // flags[0]=1, dirt[0][*]=1, rest 0
        for (int i = tid; i < FCN; i += 256)
            fc[i] = (i == 0 || (i >= RF && i < RF + NT)) ? 1 : 0;
    }

    // S1: grayscale into A (rows/cols pre-reflected so later reads are raw)
    for (int idx = tid; idx < GH * GW; idx += 256) {
        int r = idx / GW, c = idx - r * GW;
        int gyr = reflect_idx(y0 + r - 4, HH);
        int gxr = reflect_idx(x0 + c - 4, WW);
        const float* rp = base + (size_t)gyr * WW;
        double rr = (double)rp[gxr];
        double gg = (double)rp[HWP + gxr];
        double bb = (double)rp[2 * HWP + gxr];
        A[idx] = rr * 0.299 + gg * 0.587 + bb * 0.114;
    }
    __syncthreads();

    // S2: hblur into B
    for (int idx = tid; idx < HBH * HBW; idx += 256) {
        int r = idx / HBW, c = idx - r * HBW;
        const double* g = &A[r * GW + c];
        double s;
        s  = w0 * g[0];
        s += w1 * g[1];
        s += w2 * g[2];
        s += w1 * g[3];
        s += w0 * g[4];
        B[idx] = s;
    }
    __syncthreads();

    // S3: vblur into A
    for (int idx = tid; idx < VBH * VBW; idx += 256) {
        int r = idx / VBW, c = idx - r * VBW;
        const double* h = &B[r * HBW + c];
        double s;
        s  = w0 * h[0];
        s += w1 * h[1 * HBW];
        s += w2 * h[2 * HBW];
        s += w1 * h[3 * HBW];
        s += w0 * h[4 * HBW];
        A[idx] = s;
    }
    __syncthreads();

    // S4: SQUARED sobel magnitude into B (0 outside image = NMS zero pad) + dir bytes.
    for (int idx = tid; idx < MGH * MGW; idx += 256) {
        int r = idx / MGW, c = idx - r * MGW;
        int gy = y0 + r - 1, gx = x0 + c - 1;
        double mg2 = 0.0;
        if (gy >= 0 && gy < HH && gx >= 0 && gx < WW) {
            int ym = gy > 0 ? gy - 1 : 0, yp = gy < HH - 1 ? gy + 1 : HH - 1;
            int xm = gx > 0 ? gx - 1 : 0, xp = gx < WW - 1 ? gx + 1 : WW - 1;
            auto BL = [&](int yy, int xx) -> double {
                return A[(yy - y0 + 2) * VBW + (xx - x0 + 2)];
            };
            double b00 = BL(ym, xm), b01 = BL(ym, gx), b02 = BL(ym, xp);
            double b10 = BL(gy, xm),                   b12 = BL(gy, xp);
            double b20 = BL(yp, xm), b21 = BL(yp, gx), b22 = BL(yp, xp);
            double gxv = -b00 + b02 - 2.0 * b10 + 2.0 * b12 - b20 + b22;
            double gyv = -b00 - 2.0 * b01 - b02 + b20 + 2.0 * b21 + b22;
            mg2 = gxv * gxv + gyv * gyv + 1e-6;
            if (r >= 1 && r < TY + 1 && c >= 1 && c < TX + 1) {
                // octant classification == round(atan2(gy,gx)*4/pi) mod 8, boundary-exact
                double ax = fabs(gxv), ay = fabs(gyv);
                int p;
                if (ay < 0.41421356237309503 * ax)       // tan(22.5deg)
                    p = (gxv >= 0.0) ? 0 : 4;
                else if (ay < 2.4142135623730951 * ax)   // tan(67.5deg)
                    p = (gyv >= 0.0) ? ((gxv >= 0.0) ? 1 : 3)
                                     : ((gxv >= 0.0) ? 7 : 5);
                else
                    p = (gyv >= 0.0) ? 2 : 6;
                P[(r - 1) * TX + (c - 1)] = (unsigned char)p;
            }
        }
        B[r * MGW + c] = mg2;
    }
    __syncthreads();

    // S5: NMS + thresholds + ballot on squared magnitudes (one wave = one 64px row-word)
    for (int k = 0; k < (TX * TY) / 256; ++k) {
        int idx = k * 256 + tid;
        int r = idx >> 6, c = idx & 63;
        double ctr2 = B[(r + 1) * MGW + (c + 1)];
        int p = P[idx];
        int dr = ((425   >> (2 * p)) & 3) - 1;
        int dc = ((36890 >> (2 * p)) & 3) - 1;
        double mp2 = B[(r + 1 + dr) * MGW + (c + 1 + dc)];
        double mn2 = B[(r + 1 - dr) * MGW + (c + 1 - dc)];
        bool ismax = (ctr2 > mp2) && (ctr2 > mn2);      // sqrt is monotone -> same booleans
        out0[(size_t)b * HWP + (size_t)(y0 + r) * WW + (x0 + c)] =
            ismax ? (float)sqrt(ctr2) : 0.0f;
        bool strong = ismax && (ctr2 > 0.04);           // sm > 0.2
        bool weak   = ismax && (ctr2 > 0.01) && !strong;// sm > 0.1
        unsigned long long wb = __ballot(weak);
        unsigned long long sb = __ballot(strong);
        if ((tid & 63) == 0) {
            int word = (y0 + r) * WPR + (x0 >> 6);
            weakP[(size_t)b * PW + word]   = wb;
            strongP[(size_t)b * PW + word] = sb;
        }
    }
}

// ---------------- hysteresis: block-per-128x128-tile flood fill, dirty worklist ----------------
__device__ __forceinline__ unsigned long long ks_fill(unsigned long long g, unsigned long long p) {
    unsigned long long q;
    q = p;        g |= q & (g << 1);
    q &= q << 1;  g |= q & (g << 2);
    q &= q << 2;  g |= q & (g << 4);
    q &= q << 4;  g |= q & (g << 8);
    q &= q << 8;  g |= q & (g << 16);
    q &= q << 16; g |= q & (g << 32);
    q = p;        g |= q & (g >> 1);
    q &= q >> 1;  g |= q & (g >> 2);
    q &= q >> 2;  g |= q & (g >> 4);
    q &= q >> 4;  g |= q & (g >> 8);
    q &= q >> 8;  g |= q & (g >> 16);
    q &= q >> 16; g |= q & (g >> 32);
    return g;
}

// vertical Kogge-Stone closure across lanes: lane = row, g/p = 64-bit row bitmaps.
// Adds bit (r,c) if some (r',c) in g connects to it through an all-weak straight
// vertical run -- the lane-wise analog of ks_fill's doubling. Subset of the flood
// closure (4-connected vertical runs), superset of the old 1-row/iter step.
__device__ __forceinline__ unsigned long long vks_fill(unsigned long long g,
                                                       unsigned long long p, int lane) {
    unsigned long long q, t, tq;
    q = p;
    #pragma unroll
    for (int k = 1; k <= 32; k <<= 1) {
        t  = __shfl_up(g, k);  if (lane < k) t = 0;
        g |= q & t;
        tq = __shfl_up(q, k);  if (lane < k) tq = 0;
        q &= tq;
    }
    q = p;
    #pragma unroll
    for (int k = 1; k <= 32; k <<= 1) {
        t  = __shfl_down(g, k);  if (lane >= 64 - k) t = 0;
        g |= q & t;
        tq = __shfl_down(q, k);  if (lane >= 64 - k) tq = 0;
        q &= tq;
    }
    return g;
}

// 256 blocks x 256 threads; block = one 128x128 tile (2x2 waves of 64 rows x 64 cols).
// Block-local fixed point: wave-local FP in registers + inter-wave halo exchange via LDS.
// Final round writes out1 (fuses the old k_edges launch).
__global__ void __launch_bounds__(256) k_pass(const unsigned long long* __restrict__ weakP,
                                              unsigned long long* __restrict__ strongP,
                                              int* __restrict__ flags,
                                              int* __restrict__ dirt,
                                              float* __restrict__ out1, int rr) {
    __shared__ unsigned long long S[128][2];
    __shared__ int chf[4];

    const int tid  = threadIdx.x;
    const int lane = tid & 63;
    const int w    = tid >> 6;            // wave in block 0..3
    const int wy   = w >> 1, wx = w & 1;
    const int tile = blockIdx.x;          // 0..255
    const int b  = tile >> 6;
    const int ty = (tile >> 3) & 7;
    const int tx = tile & 7;
    const int tb = b << 6;

    unsigned long long* spl = strongP + (size_t)b * PW;
    const int row  = (ty << 7) + (wy << 6) + lane;   // image row
    const int wc   = (tx << 1) + wx;                 // word column 0..15
    const int wi   = row * WPR + wc;
    const int lrow = (wy << 6) + lane;               // block-local row 0..127

    const bool active = (flags[rr - 1] != 0);
    if (!active && rr != ROUNDS) return;  // globally quiet; nothing to do until final write

    int go = 0;
    if (active) {
        const int* d0 = dirt + (size_t)(rr - 1) * NT;
        if (ty > 0) { go |= d0[tb + ((ty - 1) << 3) + tx];
                      if (tx > 0) go |= d0[tb + ((ty - 1) << 3) + tx - 1];
                      if (tx < 7) go |= d0[tb + ((ty - 1) << 3) + tx + 1]; }
        if (ty < 7) { go |= d0[tb + ((ty + 1) << 3) + tx];
                      if (tx > 0) go |= d0[tb + ((ty + 1) << 3) + tx - 1];
                      if (tx < 7) go |= d0[tb + ((ty + 1) << 3) + tx + 1]; }
        if (tx > 0) go |= d0[tb + (ty << 3) + tx - 1];
        if (tx < 7) go |= d0[tb + (ty << 3) + tx + 1];
    }

    if (go) {                                        // block-uniform
        const unsigned long long* wp = weakP + (size_t)b * PW;
        unsigned long long wv = wp[wi];
        unsigned long long s  = spl[wi];

        // static external halos (Jacobi; racy-fresh reads are benign by monotonicity)
        unsigned long long ho_ext = 0;
        if (wx == 0) { if (tx > 0) ho_ext = spl[wi - 1] >> 63; }
        else         { if (tx < 7) ho_ext = spl[wi + 1] << 63; }
        unsigned long long topE = 0, botE = 0;       // full external top/bot rows
        unsigned long long topC = 0, botC = 0;       // external corner at internal rows
        if (lane == 0) {
            if (wy == 0) {
                if (ty > 0) {
                    int ra = row - 1;
                    unsigned long long hs = spl[ra * WPR + wc];
                    topE = (hs << 1) | hs | (hs >> 1);
                    if (wc > 0)  topE |= spl[ra * WPR + wc - 1] >> 63;
                    if (wc < 15) topE |= spl[ra * WPR + wc + 1] << 63;
                }
            } else {
                int rb = row - 1;                    // block-internal boundary row
                if (wx == 0) { if (tx > 0) topC = spl[rb * WPR + wc - 1] >> 63; }
                else         { if (tx < 7) topC = spl[rb * WPR + wc + 1] << 63; }
            }
        }
        if (lane == 63) {
            if (wy == 1) {
                if (ty < 7) {
                    int ra = row + 1;
                    unsigned long long hs = spl[ra * WPR + wc];
                    botE = (hs << 1) | hs | (hs >> 1);
                    if (wc > 0)  botE |= spl[ra * WPR + wc - 1] >> 63;
                    if (wc < 15) botE |= spl[ra * WPR + wc + 1] << 63;
                }
            } else {
                int rb = row + 1;
                if (wx == 0) { if (tx > 0) botC = spl[rb * WPR + wc - 1] >> 63; }
                else         { if (tx < 7) botC = spl[rb * WPR + wc + 1] << 63; }
            }
        }

        S[lrow][wx] = s;
        if (lane == 0) chf[w] = 0;
        __syncthreads();

        unsigned long long pub = s;
        int blkchanged = 0;
        for (;;) {
            // dynamic internal halos from last publish
            unsigned long long partner = S[lrow][wx ^ 1];
            unsigned long long ho = ho_ext | ((wx == 1) ? (partner >> 63) : (partner << 63));
            unsigned long long top = 0, bot = 0;
            if (lane == 0) {
                if (wy == 1) {
                    unsigned long long a = S[63][wx], p2 = S[63][wx ^ 1];
                    top = (a << 1) | a | (a >> 1) |
                          ((wx == 1) ? (p2 >> 63) : (p2 << 63)) | topC;
                } else top = topE;
            }
            if (lane == 63) {
                if (wy == 0) {
                    unsigned long long a = S[64][wx], p2 = S[64][wx ^ 1];
                    bot = (a << 1) | a | (a >> 1) |
                          ((wx == 1) ? (p2 >> 63) : (p2 << 63)) | botC;
                } else bot = botE;
            }

            // wave-local fixed point: log-depth closure in BOTH axes
            // (ks_fill horizontal, vks_fill vertical Kogge-Stone across lanes)
            for (;;) {
                unsigned long long sp = (s << 1) | s | (s >> 1) | ho;
                unsigned long long up = __shfl_up(sp, 1);
                unsigned long long dn = __shfl_down(sp, 1);
                if (lane == 0)  up = top;
                if (lane == 63) dn = bot;
                unsigned long long g = s | (wv & (up | sp | dn));
                g = ks_fill(g, wv);
                g = vks_fill(g, wv, lane);
                int ch = (g != s);
                s = g;
                if (!__any(ch)) break;
            }

            int wch = __any(s != pub);
            if (lane == 0) chf[w] = wch;
            __syncthreads();                 // (A) chf visible; all halo reads done
            S[lrow][wx] = s;
            pub = s;
            int any = chf[0] | chf[1] | chf[2] | chf[3];
            if (any) blkchanged = 1;
            __syncthreads();                 // (B) publishes visible; chf reads done
            if (!any) break;
        }

        if (blkchanged) {
            spl[wi] = s;                     // republish for next Jacobi round
            if (tid == 0) {
                dirt[(size_t)rr * NT + tb + (ty << 3) + tx] = 1;
                atomicOr(&flags[rr], 1);
            }
        }
    }

    // fused k_edges on the final round: write this block's 128x128 tile as floats.
    // When go: S holds the block's final published bits; otherwise load from global.
    if (rr == ROUNDS) {
        if (!go) S[lrow][wx] = spl[wi];
        __syncthreads();
        float* o = out1 + (size_t)b * HWP;
        for (int it = 0; it < 16; ++it) {
            int fi = (it << 8) + tid;        // float4 index within tile: 0..4095
            int r  = fi >> 5;                // 0..127
            int c4 = fi & 31;                // float4 column 0..31
            unsigned long long bits = S[r][c4 >> 4];
            int sh = (c4 & 15) << 2;
            float4 v;
            v.x = ((bits >> (sh + 0)) & 1ull) ? 1.0f : 0.0f;
            v.y = ((bits >> (sh + 1)) & 1ull) ? 1.0f : 0.0f;
            v.z = ((bits >> (sh + 2)) & 1ull) ? 1.0f : 0.0f;
            v.w = ((bits >> (sh + 3)) & 1ull) ? 1.0f : 0.0f;
            int grow = (ty << 7) + r;
            int gcol = (tx << 7) + (c4 << 2);
            *reinterpret_cast<float4*>(&o[(size_t)grow * WW + gcol]) = v;
        }
    }
}

extern "C" void kernel_launch(void* const* d_in, const int* in_sizes, int n_in,
                              void* d_out, int out_size, void* d_ws, size_t ws_size,
                              hipStream_t stream) {
    const float* x = (const float*)d_in[0];
    float* out0 = (float*)d_out;          // suppressed magnitude [4,1,1024,1024]
    float* out1 = out0 + NPIX;            // edges [4,1,1024,1024]

    // workspace: weakP | strongP | fc (flags[RF] + dirt[RF][NT])
    unsigned long long* weakP   = (unsigned long long*)d_ws;
    unsigned long long* strongP = weakP + (size_t)BB * PW;
    int* fc    = (int*)(strongP + (size_t)BB * PW);
    int* flags = fc;
    int* dirt  = fc + RF;

    // gaussian weights, f64 ops mirroring the reference
    double g0 = exp(-2.0), g1 = exp(-0.5), g2 = 1.0;
    double sum = (((g0 + g1) + g2) + g1) + g0;
    double w0 = g0 / sum, w1 = g1 / sum, w2 = g2 / sum;

    k_front<<<dim3(WW / TX, HH / TY, BB), dim3(256), 0, stream>>>(
        x, out0, weakP, strongP, fc, w0, w1, w2);

    for (int r = 1; r <= ROUNDS; ++r)
        k_pass<<<dim3(NT), dim3(256), 0, stream>>>(weakP, strongP, flags, dirt, out1, r);
}

// Round 9
// 146.026 us; speedup vs baseline: 1.0931x; 1.0623x over previous
//
#include <hip/hip_runtime.h>
#include <math.h>

static constexpr int BB  = 4;
static constexpr int HH  = 1024;
static constexpr int WW  = 1024;
static constexpr int HWP = HH * WW;       // 1<<20
static constexpr int NPIX = BB * HWP;     // 4<<20
static constexpr int WPR = WW / 64;       // 16 words per image row
static constexpr int PW  = HWP / 64;      // 16384 words per image bitplane
static constexpr int ROUNDS = 6;          // 6 rounds @128px tiles (validated round 6)
static constexpr int NT  = BB * 8 * 8;    // 256 hysteresis tiles (128x128 px, one BLOCK each)
static constexpr int RF  = ROUNDS + 1;    // flags array length
static constexpr int FCN = RF + RF * NT;  // flags[RF] + dirt[RF][NT]

// fused-stencil tile: 64 wide x 8 tall output; f64 LDS ~18.4 KB -> 8 blocks/CU
static constexpr int TX = 64, TY = 8;
static constexpr int GH = 16,  GW = 72;   // gray   (pre-reflected halo)  TY+8
static constexpr int HBH = 16, HBW = 68;  // hblur                        TY+8
static constexpr int VBH = 12, VBW = 68;  // vblur                        TY+4
static constexpr int MGH = 10, MGW = 66;  // mag^2                        TY+2

__device__ __forceinline__ int reflect_idx(int i, int n) {
    i = (i < 0) ? -i : i;                 // jnp.pad mode='reflect': -1 -> 1
    return (i >= n) ? (2 * n - 2 - i) : i;
}

// ---------- fused: gray -> hblur -> vblur -> sobel/mag^2 -> dir -> NMS -> ballot ----------
// f64 throughout (validated): f32 blur flips near-tie NMS decisions vs the reference.
__global__ void __launch_bounds__(256) k_front(const float* __restrict__ x,
                                               float* __restrict__ out0,
                                               unsigned long long* __restrict__ weakP,
                                               unsigned long long* __restrict__ strongP,
                                               int* __restrict__ fc,
                                               double w0, double w1, double w2) {
    __shared__ double A[GH * GW];         // gray, then vblur
    __shared__ double B[HBH * HBW];       // hblur, then mag^2
    __shared__ unsigned char P[TY * TX];  // quantized direction, center pixels

    const int tid = threadIdx.x;
    const int x0  = blockIdx.x * TX;
    const int y0  = blockIdx.y * TY;
    const int b   = blockIdx.z;
    const float* base = x + (size_t)b * 3u * HWP;

    if (blockIdx.x == 0 && blockIdx.y == 0 && b == 0) {
        // flags[0]=1, dirt[0][*]=1, rest 0
        for (int i = tid; i < FCN; i += 256)
            fc[i] = (i == 0 || (i >= RF && i < RF + NT)) ? 1 : 0;
    }

    // S1: grayscale into A (rows/cols pre-reflected so later reads are raw)
    for (int idx = tid; idx < GH * GW; idx += 256) {
        int r = idx / GW, c = idx - r * GW;
        int gyr = reflect_idx(y0 + r - 4, HH);
        int gxr = reflect_idx(x0 + c - 4, WW);
        const float* rp = base + (size_t)gyr * WW;
        double rr = (double)rp[gxr];
        double gg = (double)rp[HWP + gxr];
        double bb = (double)rp[2 * HWP + gxr];
        A[idx] = rr * 0.299 + gg * 0.587 + bb * 0.114;
    }
    __syncthreads();

    // S2: hblur into B
    for (int idx = tid; idx < HBH * HBW; idx += 256) {
        int r = idx / HBW, c = idx - r * HBW;
        const double* g = &A[r * GW + c];
        double s;
        s  = w0 * g[0];
        s += w1 * g[1];
        s += w2 * g[2];
        s += w1 * g[3];
        s += w0 * g[4];
        B[idx] = s;
    }
    __syncthreads();

    // S3: vblur into A
    for (int idx = tid; idx < VBH * VBW; idx += 256) {
        int r = idx / VBW, c = idx - r * VBW;
        const double* h = &B[r * HBW + c];
        double s;
        s  = w0 * h[0];
        s += w1 * h[1 * HBW];
        s += w2 * h[2 * HBW];
        s += w1 * h[3 * HBW];
        s += w0 * h[4 * HBW];
        A[idx] = s;
    }
    __syncthreads();

    // S4: SQUARED sobel magnitude into B (0 outside image = NMS zero pad) + dir bytes.
    for (int idx = tid; idx < MGH * MGW; idx += 256) {
        int r = idx / MGW, c = idx - r * MGW;
        int gy = y0 + r - 1, gx = x0 + c - 1;
        double mg2 = 0.0;
        if (gy >= 0 && gy < HH && gx >= 0 && gx < WW) {
            int ym = gy > 0 ? gy - 1 : 0, yp = gy < HH - 1 ? gy + 1 : HH - 1;
            int xm = gx > 0 ? gx - 1 : 0, xp = gx < WW - 1 ? gx + 1 : WW - 1;
            auto BL = [&](int yy, int xx) -> double {
                return A[(yy - y0 + 2) * VBW + (xx - x0 + 2)];
            };
            double b00 = BL(ym, xm), b01 = BL(ym, gx), b02 = BL(ym, xp);
            double b10 = BL(gy, xm),                   b12 = BL(gy, xp);
            double b20 = BL(yp, xm), b21 = BL(yp, gx), b22 = BL(yp, xp);
            double gxv = -b00 + b02 - 2.0 * b10 + 2.0 * b12 - b20 + b22;
            double gyv = -b00 - 2.0 * b01 - b02 + b20 + 2.0 * b21 + b22;
            mg2 = gxv * gxv + gyv * gyv + 1e-6;
            if (r >= 1 && r < TY + 1 && c >= 1 && c < TX + 1) {
                // octant classification == round(atan2(gy,gx)*4/pi) mod 8, boundary-exact
                double ax = fabs(gxv), ay = fabs(gyv);
                int p;
                if (ay < 0.41421356237309503 * ax)       // tan(22.5deg)
                    p = (gxv >= 0.0) ? 0 : 4;
                else if (ay < 2.4142135623730951 * ax)   // tan(67.5deg)
                    p = (gyv >= 0.0) ? ((gxv >= 0.0) ? 1 : 3)
                                     : ((gxv >= 0.0) ? 7 : 5);
                else
                    p = (gyv >= 0.0) ? 2 : 6;
                P[(r - 1) * TX + (c - 1)] = (unsigned char)p;
            }
        }
        B[r * MGW + c] = mg2;
    }
    __syncthreads();

    // S5: NMS + thresholds + ballot on squared magnitudes (one wave = one 64px row-word)
    for (int k = 0; k < (TX * TY) / 256; ++k) {
        int idx = k * 256 + tid;
        int r = idx >> 6, c = idx & 63;
        double ctr2 = B[(r + 1) * MGW + (c + 1)];
        int p = P[idx];
        int dr = ((425   >> (2 * p)) & 3) - 1;
        int dc = ((36890 >> (2 * p)) & 3) - 1;
        double mp2 = B[(r + 1 + dr) * MGW + (c + 1 + dc)];
        double mn2 = B[(r + 1 - dr) * MGW + (c + 1 - dc)];
        bool ismax = (ctr2 > mp2) && (ctr2 > mn2);      // sqrt is monotone -> same booleans
        out0[(size_t)b * HWP + (size_t)(y0 + r) * WW + (x0 + c)] =
            ismax ? (float)sqrt(ctr2) : 0.0f;
        bool strong = ismax && (ctr2 > 0.04);           // sm > 0.2
        bool weak   = ismax && (ctr2 > 0.01) && !strong;// sm > 0.1
        unsigned long long wb = __ballot(weak);
        unsigned long long sb = __ballot(strong);
        if ((tid & 63) == 0) {
            int word = (y0 + r) * WPR + (x0 >> 6);
            weakP[(size_t)b * PW + word]   = wb;
            strongP[(size_t)b * PW + word] = sb;
        }
    }
}

// ---------------- hysteresis: block-per-128x128-tile flood fill, dirty worklist ----------------
__device__ __forceinline__ unsigned long long ks_fill(unsigned long long g, unsigned long long p) {
    unsigned long long q;
    q = p;        g |= q & (g << 1);
    q &= q << 1;  g |= q & (g << 2);
    q &= q << 2;  g |= q & (g << 4);
    q &= q << 4;  g |= q & (g << 8);
    q &= q << 8;  g |= q & (g << 16);
    q &= q << 16; g |= q & (g << 32);
    q = p;        g |= q & (g >> 1);
    q &= q >> 1;  g |= q & (g >> 2);
    q &= q >> 2;  g |= q & (g >> 4);
    q &= q >> 4;  g |= q & (g >> 8);
    q &= q >> 8;  g |= q & (g >> 16);
    q &= q >> 16; g |= q & (g >> 32);
    return g;
}

// 256 blocks x 256 threads; block = one 128x128 tile (2x2 waves of 64 rows x 64 cols).
// Block-local fixed point: wave-local FP in registers + inter-wave halo exchange via LDS.
// Dirty tracking is EXPORT-based: a tile marks itself dirty only if the values its
// neighbors actually read (row 0, row 127, edge-column bits) changed -- interior-only
// convergence stops waking neighbors (exact: unchanged exports => neighbors' re-run
// would be a no-op). Final round writes out1 (fused k_edges).
__global__ void __launch_bounds__(256) k_pass(const unsigned long long* __restrict__ weakP,
                                              unsigned long long* __restrict__ strongP,
                                              int* __restrict__ flags,
                                              int* __restrict__ dirt,
                                              float* __restrict__ out1, int rr) {
    __shared__ unsigned long long S[128][2];
    __shared__ int chf[4];

    const int tid  = threadIdx.x;
    const int lane = tid & 63;
    const int w    = tid >> 6;            // wave in block 0..3
    const int wy   = w >> 1, wx = w & 1;
    const int tile = blockIdx.x;          // 0..255
    const int b  = tile >> 6;
    const int ty = (tile >> 3) & 7;
    const int tx = tile & 7;
    const int tb = b << 6;

    unsigned long long* spl = strongP + (size_t)b * PW;
    const int row  = (ty << 7) + (wy << 6) + lane;   // image row
    const int wc   = (tx << 1) + wx;                 // word column 0..15
    const int wi   = row * WPR + wc;
    const int lrow = (wy << 6) + lane;               // block-local row 0..127

    const bool active = (flags[rr - 1] != 0);
    if (!active && rr != ROUNDS) return;  // globally quiet; nothing to do until final write

    int go = 0;
    if (active) {
        const int* d0 = dirt + (size_t)(rr - 1) * NT;
        if (ty > 0) { go |= d0[tb + ((ty - 1) << 3) + tx];
                      if (tx > 0) go |= d0[tb + ((ty - 1) << 3) + tx - 1];
                      if (tx < 7) go |= d0[tb + ((ty - 1) << 3) + tx + 1]; }
        if (ty < 7) { go |= d0[tb + ((ty + 1) << 3) + tx];
                      if (tx > 0) go |= d0[tb + ((ty + 1) << 3) + tx - 1];
                      if (tx < 7) go |= d0[tb + ((ty + 1) << 3) + tx + 1]; }
        if (tx > 0) go |= d0[tb + (ty << 3) + tx - 1];
        if (tx < 7) go |= d0[tb + (ty << 3) + tx + 1];
    }

    if (go) {                                        // block-uniform
        const unsigned long long* wp = weakP + (size_t)b * PW;
        unsigned long long wv = wp[wi];
        unsigned long long s  = spl[wi];
        const unsigned long long sorig = s;          // for export-change detection

        // static external halos (Jacobi; racy-fresh reads are benign by monotonicity)
        unsigned long long ho_ext = 0;
        if (wx == 0) { if (tx > 0) ho_ext = spl[wi - 1] >> 63; }
        else         { if (tx < 7) ho_ext = spl[wi + 1] << 63; }
        unsigned long long topE = 0, botE = 0;       // full external top/bot rows
        unsigned long long topC = 0, botC = 0;       // external corner at internal rows
        if (lane == 0) {
            if (wy == 0) {
                if (ty > 0) {
                    int ra = row - 1;
                    unsigned long long hs = spl[ra * WPR + wc];
                    topE = (hs << 1) | hs | (hs >> 1);
                    if (wc > 0)  topE |= spl[ra * WPR + wc - 1] >> 63;
                    if (wc < 15) topE |= spl[ra * WPR + wc + 1] << 63;
                }
            } else {
                int rb = row - 1;                    // block-internal boundary row
                if (wx == 0) { if (tx > 0) topC = spl[rb * WPR + wc - 1] >> 63; }
                else         { if (tx < 7) topC = spl[rb * WPR + wc + 1] << 63; }
            }
        }
        if (lane == 63) {
            if (wy == 1) {
                if (ty < 7) {
                    int ra = row + 1;
                    unsigned long long hs = spl[ra * WPR + wc];
                    botE = (hs << 1) | hs | (hs >> 1);
                    if (wc > 0)  botE |= spl[ra * WPR + wc - 1] >> 63;
                    if (wc < 15) botE |= spl[ra * WPR + wc + 1] << 63;
                }
            } else {
                int rb = row + 1;
                if (wx == 0) { if (tx > 0) botC = spl[rb * WPR + wc - 1] >> 63; }
                else         { if (tx < 7) botC = spl[rb * WPR + wc + 1] << 63; }
            }
        }

        S[lrow][wx] = s;
        if (lane == 0) chf[w] = 0;
        __syncthreads();

        unsigned long long pub = s;
        int blkchanged = 0;
        for (;;) {
            // dynamic internal halos from last publish
            unsigned long long partner = S[lrow][wx ^ 1];
            unsigned long long ho = ho_ext | ((wx == 1) ? (partner >> 63) : (partner << 63));
            unsigned long long top = 0, bot = 0;
            if (lane == 0) {
                if (wy == 1) {
                    unsigned long long a = S[63][wx], p2 = S[63][wx ^ 1];
                    top = (a << 1) | a | (a >> 1) |
                          ((wx == 1) ? (p2 >> 63) : (p2 << 63)) | topC;
                } else top = topE;
            }
            if (lane == 63) {
                if (wy == 0) {
                    unsigned long long a = S[64][wx], p2 = S[64][wx ^ 1];
                    bot = (a << 1) | a | (a >> 1) |
                          ((wx == 1) ? (p2 >> 63) : (p2 << 63)) | botC;
                } else bot = botE;
            }

            // one 8-neighbor dilate-and-mask step (cheap: ~12 ops, propagates 1 px any dir)
            auto step = [&](unsigned long long v) -> unsigned long long {
                unsigned long long sp = (v << 1) | v | (v >> 1) | ho;
                unsigned long long up = __shfl_up(sp, 1);
                unsigned long long dn = __shfl_down(sp, 1);
                if (lane == 0)  up = top;
                if (lane == 63) dn = bot;
                return v | (wv & (up | sp | dn));
            };

            // wave-local fixed point. Per iteration: step + ks_fill (closes horizontal
            // runs log-time) + 3 more cheap steps (4 px/iter along snaky ridges vs 1).
            // Superset of the old per-iter growth, subset of the closure => same FP.
            for (;;) {
                unsigned long long g = step(s);
                g = ks_fill(g, wv);
                g = step(g);
                g = step(g);
                g = step(g);
                int ch = (g != s);
                s = g;
                if (!__any(ch)) break;
            }

            int wch = __any(s != pub);
            if (lane == 0) chf[w] = wch;
            __syncthreads();                 // (A) chf visible; all halo reads done
            S[lrow][wx] = s;
            pub = s;
            int any = chf[0] | chf[1] | chf[2] | chf[3];
            if (any) blkchanged = 1;
            __syncthreads();                 // (B) publishes visible; chf reads done
            if (!any) break;
        }

        // export-change detection: row 0 / row 127 words; edge-column bits per row
        unsigned long long sx = s ^ sorig;
        int expch = 0;
        if ((wy == 0 && lane == 0) || (wy == 1 && lane == 63)) expch |= (sx != 0);
        expch |= (wx == 0) ? (int)(sx & 1ull) : (int)((sx >> 63) & 1ull);
        int wexp = __any(expch);
        if (lane == 0) chf[w] = wexp;        // chf free after loop exit (post-sync B)
        __syncthreads();
        int expany = chf[0] | chf[1] | chf[2] | chf[3];

        if (blkchanged) {
            spl[wi] = s;                     // republish (interior too: final write needs it)
            if (tid == 0 && expany) {
                dirt[(size_t)rr * NT + tb + (ty << 3) + tx] = 1;
                atomicOr(&flags[rr], 1);
            }
        }
    }

    // fused k_edges on the final round: write this block's 128x128 tile as floats.
    // When go: S holds the block's final published bits; otherwise load from global.
    if (rr == ROUNDS) {
        if (!go) S[lrow][wx] = spl[wi];
        __syncthreads();
        float* o = out1 + (size_t)b * HWP;
        for (int it = 0; it < 16; ++it) {
            int fi = (it << 8) + tid;        // float4 index within tile: 0..4095
            int r  = fi >> 5;                // 0..127
            int c4 = fi & 31;                // float4 column 0..31
            unsigned long long bits = S[r][c4 >> 4];
            int sh = (c4 & 15) << 2;
            float4 v;
            v.x = ((bits >> (sh + 0)) & 1ull) ? 1.0f : 0.0f;
            v.y = ((bits >> (sh + 1)) & 1ull) ? 1.0f : 0.0f;
            v.z = ((bits >> (sh + 2)) & 1ull) ? 1.0f : 0.0f;
            v.w = ((bits >> (sh + 3)) & 1ull) ? 1.0f : 0.0f;
            int grow = (ty << 7) + r;
            int gcol = (tx << 7) + (c4 << 2);
            *reinterpret_cast<float4*>(&o[(size_t)grow * WW + gcol]) = v;
        }
    }
}

extern "C" void kernel_launch(void* const* d_in, const int* in_sizes, int n_in,
                              void* d_out, int out_size, void* d_ws, size_t ws_size,
                              hipStream_t stream) {
    const float* x = (const float*)d_in[0];
    float* out0 = (float*)d_out;          // suppressed magnitude [4,1,1024,1024]
    float* out1 = out0 + NPIX;            // edges [4,1,1024,1024]

    // workspace: weakP | strongP | fc (flags[RF] + dirt[RF][NT])
    unsigned long long* weakP   = (unsigned long long*)d_ws;
    unsigned long long* strongP = weakP + (size_t)BB * PW;
    int* fc    = (int*)(strongP + (size_t)BB * PW);
    int* flags = fc;
    int* dirt  = fc + RF;

    // gaussian weights, f64 ops mirroring the reference
    double g0 = exp(-2.0), g1 = exp(-0.5), g2 = 1.0;
    double sum = (((g0 + g1) + g2) + g1) + g0;
    double w0 = g0 / sum, w1 = g1 / sum, w2 = g2 / sum;

    k_front<<<dim3(WW / TX, HH / TY, BB), dim3(256), 0, stream>>>(
        x, out0, weakP, strongP, fc, w0, w1, w2);

    for (int r = 1; r <= ROUNDS; ++r)
        k_pass<<<dim3(NT), dim3(256), 0, stream>>>(weakP, strongP, flags, dirt, out1, r);
}

// Round 10
// 140.840 us; speedup vs baseline: 1.1333x; 1.0368x over previous
//
#include <hip/hip_runtime.h>
#include <math.h>

static constexpr int BB  = 4;
static constexpr int HH  = 1024;
static constexpr int WW  = 1024;
static constexpr int HWP = HH * WW;       // 1<<20
static constexpr int NPIX = BB * HWP;     // 4<<20
static constexpr int WPR = WW / 64;       // 16 words per image row
static constexpr int PW  = HWP / 64;      // 16384 words per image bitplane
static constexpr int ROUNDS = 6;          // 6 rounds @128px tiles (validated round 6)
static constexpr int NT  = BB * 8 * 8;    // 256 hysteresis tiles (128x128 px, one BLOCK each)
static constexpr int RF  = ROUNDS + 1;    // dirt rounds 0..ROUNDS
static constexpr int FCN = RF * NT;       // dirt[RF][NT] (no global flags -- see k_pass)

// fused-stencil tile: 64 wide x 8 tall output; f64 LDS ~18.4 KB -> 8 blocks/CU
static constexpr int TX = 64, TY = 8;
static constexpr int GH = 16,  GW = 72;   // gray   (pre-reflected halo)  TY+8
static constexpr int HBH = 16, HBW = 68;  // hblur                        TY+8
static constexpr int VBH = 12, VBW = 68;  // vblur                        TY+4
static constexpr int MGH = 10, MGW = 66;  // mag^2                        TY+2

__device__ __forceinline__ int reflect_idx(int i, int n) {
    i = (i < 0) ? -i : i;                 // jnp.pad mode='reflect': -1 -> 1
    return (i >= n) ? (2 * n - 2 - i) : i;
}

// ---------- fused: gray -> hblur -> vblur -> sobel/mag^2 -> dir -> NMS -> ballot ----------
// f64 throughout (validated): f32 blur flips near-tie NMS decisions vs the reference.
__global__ void __launch_bounds__(256) k_front(const float* __restrict__ x,
                                               float* __restrict__ out0,
                                               unsigned long long* __restrict__ weakP,
                                               unsigned long long* __restrict__ strongP,
                                               int* __restrict__ fc,
                                               double w0, double w1, double w2) {
    __shared__ double A[GH * GW];         // gray, then vblur
    __shared__ double B[HBH * HBW];       // hblur, then mag^2
    __shared__ unsigned char P[TY * TX];  // quantized direction, center pixels

    const int tid = threadIdx.x;
    const int x0  = blockIdx.x * TX;
    const int y0  = blockIdx.y * TY;
    const int b   = blockIdx.z;
    const float* base = x + (size_t)b * 3u * HWP;

    if (blockIdx.x == 0 && blockIdx.y == 0 && b == 0) {
        // dirt[0][*]=1, rest 0
        for (int i = tid; i < FCN; i += 256)
            fc[i] = (i < NT) ? 1 : 0;
    }

    // S1: grayscale into A (rows/cols pre-reflected so later reads are raw)
    for (int idx = tid; idx < GH * GW; idx += 256) {
        int r = idx / GW, c = idx - r * GW;
        int gyr = reflect_idx(y0 + r - 4, HH);
        int gxr = reflect_idx(x0 + c - 4, WW);
        const float* rp = base + (size_t)gyr * WW;
        double rr = (double)rp[gxr];
        double gg = (double)rp[HWP + gxr];
        double bb = (double)rp[2 * HWP + gxr];
        A[idx] = rr * 0.299 + gg * 0.587 + bb * 0.114;
    }
    __syncthreads();

    // S2: hblur into B
    for (int idx = tid; idx < HBH * HBW; idx += 256) {
        int r = idx / HBW, c = idx - r * HBW;
        const double* g = &A[r * GW + c];
        double s;
        s  = w0 * g[0];
        s += w1 * g[1];
        s += w2 * g[2];
        s += w1 * g[3];
        s += w0 * g[4];
        B[idx] = s;
    }
    __syncthreads();

    // S3: vblur into A
    for (int idx = tid; idx < VBH * VBW; idx += 256) {
        int r = idx / VBW, c = idx - r * VBW;
        const double* h = &B[r * HBW + c];
        double s;
        s  = w0 * h[0];
        s += w1 * h[1 * HBW];
        s += w2 * h[2 * HBW];
        s += w1 * h[3 * HBW];
        s += w0 * h[4 * HBW];
        A[idx] = s;
    }
    __syncthreads();

    // S4: SQUARED sobel magnitude into B (0 outside image = NMS zero pad) + dir bytes.
    for (int idx = tid; idx < MGH * MGW; idx += 256) {
        int r = idx / MGW, c = idx - r * MGW;
        int gy = y0 + r - 1, gx = x0 + c - 1;
        double mg2 = 0.0;
        if (gy >= 0 && gy < HH && gx >= 0 && gx < WW) {
            int ym = gy > 0 ? gy - 1 : 0, yp = gy < HH - 1 ? gy + 1 : HH - 1;
            int xm = gx > 0 ? gx - 1 : 0, xp = gx < WW - 1 ? gx + 1 : WW - 1;
            auto BL = [&](int yy, int xx) -> double {
                return A[(yy - y0 + 2) * VBW + (xx - x0 + 2)];
            };
            double b00 = BL(ym, xm), b01 = BL(ym, gx), b02 = BL(ym, xp);
            double b10 = BL(gy, xm),                   b12 = BL(gy, xp);
            double b20 = BL(yp, xm), b21 = BL(yp, gx), b22 = BL(yp, xp);
            double gxv = -b00 + b02 - 2.0 * b10 + 2.0 * b12 - b20 + b22;
            double gyv = -b00 - 2.0 * b01 - b02 + b20 + 2.0 * b21 + b22;
            mg2 = gxv * gxv + gyv * gyv + 1e-6;
            if (r >= 1 && r < TY + 1 && c >= 1 && c < TX + 1) {
                // octant classification == round(atan2(gy,gx)*4/pi) mod 8, boundary-exact
                double ax = fabs(gxv), ay = fabs(gyv);
                int p;
                if (ay < 0.41421356237309503 * ax)       // tan(22.5deg)
                    p = (gxv >= 0.0) ? 0 : 4;
                else if (ay < 2.4142135623730951 * ax)   // tan(67.5deg)
                    p = (gyv >= 0.0) ? ((gxv >= 0.0) ? 1 : 3)
                                     : ((gxv >= 0.0) ? 7 : 5);
                else
                    p = (gyv >= 0.0) ? 2 : 6;
                P[(r - 1) * TX + (c - 1)] = (unsigned char)p;
            }
        }
        B[r * MGW + c] = mg2;
    }
    __syncthreads();

    // S5: NMS + thresholds + ballot on squared magnitudes (one wave = one 64px row-word)
    for (int k = 0; k < (TX * TY) / 256; ++k) {
        int idx = k * 256 + tid;
        int r = idx >> 6, c = idx & 63;
        double ctr2 = B[(r + 1) * MGW + (c + 1)];
        int p = P[idx];
        int dr = ((425   >> (2 * p)) & 3) - 1;
        int dc = ((36890 >> (2 * p)) & 3) - 1;
        double mp2 = B[(r + 1 + dr) * MGW + (c + 1 + dc)];
        double mn2 = B[(r + 1 - dr) * MGW + (c + 1 - dc)];
        bool ismax = (ctr2 > mp2) && (ctr2 > mn2);      // sqrt is monotone -> same booleans
        out0[(size_t)b * HWP + (size_t)(y0 + r) * WW + (x0 + c)] =
            ismax ? (float)sqrt(ctr2) : 0.0f;
        bool strong = ismax && (ctr2 > 0.04);           // sm > 0.2
        bool weak   = ismax && (ctr2 > 0.01) && !strong;// sm > 0.1
        unsigned long long wb = __ballot(weak);
        unsigned long long sb = __ballot(strong);
        if ((tid & 63) == 0) {
            int word = (y0 + r) * WPR + (x0 >> 6);
            weakP[(size_t)b * PW + word]   = wb;
            strongP[(size_t)b * PW + word] = sb;
        }
    }
}

// ---------------- hysteresis: block-per-128x128-tile flood fill, dirty worklist ----------------
__device__ __forceinline__ unsigned long long ks_fill(unsigned long long g, unsigned long long p) {
    unsigned long long q;
    q = p;        g |= q & (g << 1);
    q &= q << 1;  g |= q & (g << 2);
    q &= q << 2;  g |= q & (g << 4);
    q &= q << 4;  g |= q & (g << 8);
    q &= q << 8;  g |= q & (g << 16);
    q &= q << 16; g |= q & (g << 32);
    q = p;        g |= q & (g >> 1);
    q &= q >> 1;  g |= q & (g >> 2);
    q &= q >> 2;  g |= q & (g >> 4);
    q &= q >> 4;  g |= q & (g >> 8);
    q &= q >> 8;  g |= q & (g >> 16);
    q &= q >> 16; g |= q & (g >> 32);
    return g;
}

// 256 blocks x 256 threads; block = one 128x128 tile (2x2 waves of 64 rows x 64 cols).
// Block-local fixed point: wave-local FP in registers + inter-wave halo exchange via LDS.
// NO global flags / NO atomicOr: the single shared flags word was a 256-writer
// cross-XCD cacheline ping-pong (G12) -- with 1 wave/CU and zero TLP every block ate
// the full serialized round-trip. The go-decision derives purely from the per-tile
// dirt ring (plain stores, one writer per slot). Semantics identical: flags was only
// a shortcut for globally-quiet rounds; those now cost the same ~2us via all-blocks
// seeing an empty ring. Final round writes out1 (fused k_edges).
__global__ void __launch_bounds__(256) k_pass(const unsigned long long* __restrict__ weakP,
                                              unsigned long long* __restrict__ strongP,
                                              int* __restrict__ dirt,
                                              float* __restrict__ out1, int rr) {
    __shared__ unsigned long long S[128][2];
    __shared__ int chf[4];

    const int tid  = threadIdx.x;
    const int lane = tid & 63;
    const int w    = tid >> 6;            // wave in block 0..3
    const int wy   = w >> 1, wx = w & 1;
    const int tile = blockIdx.x;          // 0..255
    const int b  = tile >> 6;
    const int ty = (tile >> 3) & 7;
    const int tx = tile & 7;
    const int tb = b << 6;

    unsigned long long* spl = strongP + (size_t)b * PW;
    const int row  = (ty << 7) + (wy << 6) + lane;   // image row
    const int wc   = (tx << 1) + wx;                 // word column 0..15
    const int wi   = row * WPR + wc;
    const int lrow = (wy << 6) + lane;               // block-local row 0..127

    // re-run only if an 8-neighbor tile changed last round (self at FP if halos unchanged)
    const int* d0 = dirt + (size_t)(rr - 1) * NT;
    int go = 0;
    if (ty > 0) { go |= d0[tb + ((ty - 1) << 3) + tx];
                  if (tx > 0) go |= d0[tb + ((ty - 1) << 3) + tx - 1];
                  if (tx < 7) go |= d0[tb + ((ty - 1) << 3) + tx + 1]; }
    if (ty < 7) { go |= d0[tb + ((ty + 1) << 3) + tx];
                  if (tx > 0) go |= d0[tb + ((ty + 1) << 3) + tx - 1];
                  if (tx < 7) go |= d0[tb + ((ty + 1) << 3) + tx + 1]; }
    if (tx > 0) go |= d0[tb + (ty << 3) + tx - 1];
    if (tx < 7) go |= d0[tb + (ty << 3) + tx + 1];

    if (!go && rr != ROUNDS) return;      // wave-uniform; final round continues to out1 write

    if (go) {                                        // block-uniform
        const unsigned long long* wp = weakP + (size_t)b * PW;
        unsigned long long wv = wp[wi];
        unsigned long long s  = spl[wi];

        // static external halos (Jacobi; racy-fresh reads are benign by monotonicity)
        unsigned long long ho_ext = 0;
        if (wx == 0) { if (tx > 0) ho_ext = spl[wi - 1] >> 63; }
        else         { if (tx < 7) ho_ext = spl[wi + 1] << 63; }
        unsigned long long topE = 0, botE = 0;       // full external top/bot rows
        unsigned long long topC = 0, botC = 0;       // external corner at internal rows
        if (lane == 0) {
            if (wy == 0) {
                if (ty > 0) {
                    int ra = row - 1;
                    unsigned long long hs = spl[ra * WPR + wc];
                    topE = (hs << 1) | hs | (hs >> 1);
                    if (wc > 0)  topE |= spl[ra * WPR + wc - 1] >> 63;
                    if (wc < 15) topE |= spl[ra * WPR + wc + 1] << 63;
                }
            } else {
                int rb = row - 1;                    // block-internal boundary row
                if (wx == 0) { if (tx > 0) topC = spl[rb * WPR + wc - 1] >> 63; }
                else         { if (tx < 7) topC = spl[rb * WPR + wc + 1] << 63; }
            }
        }
        if (lane == 63) {
            if (wy == 1) {
                if (ty < 7) {
                    int ra = row + 1;
                    unsigned long long hs = spl[ra * WPR + wc];
                    botE = (hs << 1) | hs | (hs >> 1);
                    if (wc > 0)  botE |= spl[ra * WPR + wc - 1] >> 63;
                    if (wc < 15) botE |= spl[ra * WPR + wc + 1] << 63;
                }
            } else {
                int rb = row + 1;
                if (wx == 0) { if (tx > 0) botC = spl[rb * WPR + wc - 1] >> 63; }
                else         { if (tx < 7) botC = spl[rb * WPR + wc + 1] << 63; }
            }
        }

        S[lrow][wx] = s;
        if (lane == 0) chf[w] = 0;
        __syncthreads();

        unsigned long long pub = s;
        int blkchanged = 0;
        for (;;) {
            // dynamic internal halos from last publish
            unsigned long long partner = S[lrow][wx ^ 1];
            unsigned long long ho = ho_ext | ((wx == 1) ? (partner >> 63) : (partner << 63));
            unsigned long long top = 0, bot = 0;
            if (lane == 0) {
                if (wy == 1) {
                    unsigned long long a = S[63][wx], p2 = S[63][wx ^ 1];
                    top = (a << 1) | a | (a >> 1) |
                          ((wx == 1) ? (p2 >> 63) : (p2 << 63)) | topC;
                } else top = topE;
            }
            if (lane == 63) {
                if (wy == 0) {
                    unsigned long long a = S[64][wx], p2 = S[64][wx ^ 1];
                    bot = (a << 1) | a | (a >> 1) |
                          ((wx == 1) ? (p2 >> 63) : (p2 << 63)) | botC;
                } else bot = botE;
            }

            // wave-local fixed point: shuffles vertical, ks_fill horizontal
            for (;;) {
                unsigned long long sp = (s << 1) | s | (s >> 1) | ho;
                unsigned long long up = __shfl_up(sp, 1);
                unsigned long long dn = __shfl_down(sp, 1);
                if (lane == 0)  up = top;
                if (lane == 63) dn = bot;
                unsigned long long g = s | (wv & (up | sp | dn));
                g = ks_fill(g, wv);
                int ch = (g != s);
                s = g;
                if (!__any(ch)) break;
            }

            int wch = __any(s != pub);
            if (lane == 0) chf[w] = wch;
            __syncthreads();                 // (A) chf visible; all halo reads done
            S[lrow][wx] = s;
            pub = s;
            int any = chf[0] | chf[1] | chf[2] | chf[3];
            if (any) blkchanged = 1;
            __syncthreads();                 // (B) publishes visible; chf reads done
            if (!any) break;
        }

        if (blkchanged) {
            spl[wi] = s;                     // republish for next Jacobi round
            if (tid == 0)
                dirt[(size_t)rr * NT + tb + (ty << 3) + tx] = 1;  // plain store, sole writer
        }
    }

    // fused k_edges on the final round: write this block's 128x128 tile as floats.
    // When go: S holds the block's final published bits; otherwise load from global.
    if (rr == ROUNDS) {
        if (!go) S[lrow][wx] = spl[wi];
        __syncthreads();
        float* o = out1 + (size_t)b * HWP;
        for (int it = 0; it < 16; ++it) {
            int fi = (it << 8) + tid;        // float4 index within tile: 0..4095
            int r  = fi >> 5;                // 0..127
            int c4 = fi & 31;                // float4 column 0..31
            unsigned long long bits = S[r][c4 >> 4];
            int sh = (c4 & 15) << 2;
            float4 v;
            v.x = ((bits >> (sh + 0)) & 1ull) ? 1.0f : 0.0f;
            v.y = ((bits >> (sh + 1)) & 1ull) ? 1.0f : 0.0f;
            v.z = ((bits >> (sh + 2)) & 1ull) ? 1.0f : 0.0f;
            v.w = ((bits >> (sh + 3)) & 1ull) ? 1.0f : 0.0f;
            int grow = (ty << 7) + r;
            int gcol = (tx << 7) + (c4 << 2);
            *reinterpret_cast<float4*>(&o[(size_t)grow * WW + gcol]) = v;
        }
    }
}

extern "C" void kernel_launch(void* const* d_in, const int* in_sizes, int n_in,
                              void* d_out, int out_size, void* d_ws, size_t ws_size,
                              hipStream_t stream) {
    const float* x = (const float*)d_in[0];
    float* out0 = (float*)d_out;          // suppressed magnitude [4,1,1024,1024]
    float* out1 = out0 + NPIX;            // edges [4,1,1024,1024]

    // workspace: weakP | strongP | dirt[RF][NT]
    unsigned long long* weakP   = (unsigned long long*)d_ws;
    unsigned long long* strongP = weakP + (size_t)BB * PW;
    int* dirt = (int*)(strongP + (size_t)BB * PW);

    // gaussian weights, f64 ops mirroring the reference
    double g0 = exp(-2.0), g1 = exp(-0.5), g2 = 1.0;
    double sum = (((g0 + g1) + g2) + g1) + g0;
    double w0 = g0 / sum, w1 = g1 / sum, w2 = g2 / sum;

    k_front<<<dim3(WW / TX, HH / TY, BB), dim3(256), 0, stream>>>(
        x, out0, weakP, strongP, dirt, w0, w1, w2);

    for (int r = 1; r <= ROUNDS; ++r)
        k_pass<<<dim3(NT), dim3(256), 0, stream>>>(weakP, strongP, dirt, out1, r);
}